// Round 5
// baseline (64.917 us; speedup 1.0000x reference)
//
#include <hip/hip_runtime.h>
#include <hip/hip_bf16.h>

// Oja scan, reformulated:
//   pre_t = P_{t-1} * ( G_t + sum_{s<t} a_s * S[s,t] ),  a_s = c2_s/P_s,
//   c1=1-lr*y^2, c2=lr*y, P_t = prod c1.
// Kernel 1 (MFMA GEMM): G[b][n][t], n in [0,1088): rows 0..1023 = W0 rows,
// rows 1024..1087 = X rows (=> S = X X^T). Pure 34 MB HBM stream of W.
// R5: 16-wave blocks with 4-way K-split (TLP) + explicit depth-1 register
// prefetch (ILP) to keep >=4 loads in flight per wave. LDS-reduce partials.
// Kernel 2 (scan): per-row 64-step scalar scan, t-axis across lanes.

#define BB 8
#define TT 64
#define NI 1024
#define NO 1024
#define NTOT 1088            // 1024 W rows + 64 X rows
#define NTILES 68            // NTOT/16
#define KS 4                 // K-slices per block
#define KSL 256              // NI/KS, K per wave
#define KIT 8                // KSL/32 MFMA steps per wave

typedef __attribute__((ext_vector_type(8))) short bf16x8;
typedef __attribute__((ext_vector_type(4))) float f32x4;

__device__ __forceinline__ short f2bf(float f) {
    __hip_bfloat16 h = __float2bfloat16(f);
    return __builtin_bit_cast(short, h);
}

__device__ __forceinline__ bf16x8 cvt8(float4 lo, float4 hi) {
    bf16x8 r;
    r[0] = f2bf(lo.x); r[1] = f2bf(lo.y); r[2] = f2bf(lo.z); r[3] = f2bf(lo.w);
    r[4] = f2bf(hi.x); r[5] = f2bf(hi.y); r[6] = f2bf(hi.z); r[7] = f2bf(hi.w);
    return r;
}

// ---------- Kernel 1: G[b][n][t] = row_n . x_t via MFMA ----------
// Block: 1024 thr = 16 waves = 4 t-tiles x 4 K-slices, one 16-row n-tile.
__global__ __launch_bounds__(1024, 4)
void gemm_kernel(const float* __restrict__ X, const float* __restrict__ W0,
                 float* __restrict__ G)
{
    __shared__ float red[KS][16][TT];   // 16 KB partials

    const int lane = threadIdx.x & 63;
    const int wave = threadIdx.x >> 6;
    const int tt   = wave & 3;          // t-tile 0..3
    const int ks   = wave >> 2;         // K-slice 0..3
    const int b  = blockIdx.x / NTILES;
    const int nt = blockIdx.x % NTILES;
    const int n0 = nt * 16;
    const int t0 = tt * 16;

    const int r  = lane & 15;           // row within tile
    const int kb = lane >> 4;           // k-block 0..3 (8 k's each)

    const float* __restrict__ Arow =
        (n0 < NO ? W0 + ((size_t)b * NO + n0 + r) * NI
                 : X  + ((size_t)b * TT + (n0 - NO) + r) * NI) + ks * KSL + kb * 8;
    const float* __restrict__ Brow =
        X + ((size_t)b * TT + t0 + r) * NI + ks * KSL + kb * 8;

    f32x4 acc = {0.f, 0.f, 0.f, 0.f};

    // depth-1 register prefetch rotation
    float4 a0 = *reinterpret_cast<const float4*>(Arow);
    float4 a1 = *reinterpret_cast<const float4*>(Arow + 4);
    float4 b0 = *reinterpret_cast<const float4*>(Brow);
    float4 b1 = *reinterpret_cast<const float4*>(Brow + 4);

#pragma unroll
    for (int it = 0; it < KIT; ++it) {
        float4 na0, na1, nb0, nb1;
        if (it + 1 < KIT) {
            const int o = (it + 1) * 32;
            na0 = *reinterpret_cast<const float4*>(Arow + o);
            na1 = *reinterpret_cast<const float4*>(Arow + o + 4);
            nb0 = *reinterpret_cast<const float4*>(Brow + o);
            nb1 = *reinterpret_cast<const float4*>(Brow + o + 4);
        }
        const bf16x8 a  = cvt8(a0, a1);
        const bf16x8 bv = cvt8(b0, b1);
        acc = __builtin_amdgcn_mfma_f32_16x16x32_bf16(a, bv, acc, 0, 0, 0);
        if (it + 1 < KIT) { a0 = na0; a1 = na1; b0 = nb0; b1 = nb1; }
    }

    // D layout: col t = lane&15, row n = (lane>>4)*4 + rr   [m89-verified]
    const int tcol = lane & 15;
    const int mrow = (lane >> 4) * 4;
#pragma unroll
    for (int rr = 0; rr < 4; ++rr)
        red[ks][mrow + rr][t0 + tcol] = acc[rr];

    __syncthreads();

    // reduce 4 K-slices; thread tid -> (n, t)
    const int n = threadIdx.x >> 6;     // 0..15
    const int t = threadIdx.x & 63;     // 0..63
    const float g = red[0][n][t] + red[1][n][t] + red[2][n][t] + red[3][n][t];
    G[((size_t)b * NTOT + n0 + n) * TT + t] = g;
}

// ---------- Kernel 2: scalar scan per (b,o) row ----------
__global__ __launch_bounds__(512, 8)
void scan_kernel(const float* __restrict__ G, float* __restrict__ out)
{
    __shared__ float Sl[TT][TT];      // 16 KB: S[b]
    __shared__ float ybuf[8][TT + 1]; // per-wave y trajectory (padded)

    const int tid  = threadIdx.x;
    const int lane = tid & 63;
    const int wave = tid >> 6;
    const int row  = blockIdx.x * 8 + wave;   // 0..8191
    const int b = row >> 10;                  // 128 blocks per batch
    const int o = row & 1023;

    // stage S[b] = G rows 1024..1087 (4096 contiguous floats)
    {
        const float4* __restrict__ src =
            reinterpret_cast<const float4*>(G + ((size_t)b * NTOT + NO) * TT);
        float4* dst = reinterpret_cast<float4*>(&Sl[0][0]);
        dst[tid]       = src[tid];
        dst[tid + 512] = src[tid + 512];
    }

    // acc[lane=t] = G_t for this row (contiguous 64 floats)
    float acc = G[((size_t)b * NTOT + o) * TT + lane];

    __syncthreads();

    const float lr = 1.0f / 1024.0f;
    float P = 1.0f;
    float yslot = 0.0f;
    float srow = Sl[0][lane];
#pragma unroll
    for (int t = 0; t < TT; ++t) {
        const float srow_next = (t + 1 < TT) ? Sl[t + 1][lane] : 0.0f;
        const float sg  = __int_as_float(__builtin_amdgcn_readlane(__float_as_int(acc), t));
        const float pre = P * sg;
        const float e   = __expf(-pre);
        const float y   = __builtin_amdgcn_rcpf(1.0f + e);
        yslot = (lane == t) ? y : yslot;
        const float c2 = lr * y;
        const float c1 = fmaf(-c2, y, 1.0f);   // 1 - lr*y^2
        P *= c1;
        const float a = c2 * __builtin_amdgcn_rcpf(P);
        acc = fmaf(a, srow, acc);              // lanes <= t: garbage, never read
        srow = srow_next;
    }

    // coalesce the output: bounce through LDS, then 32B-contiguous stores
    ybuf[wave][lane] = yslot;                  // lane = t
    __syncthreads();
    const int t  = tid >> 3;                   // 0..63
    const int oo = tid & 7;                    // 0..7
    const int o0 = (blockIdx.x & 127) * 8;
    out[(size_t)b * TT * NO + (size_t)t * NO + o0 + oo] = ybuf[oo][t];
}

extern "C" void kernel_launch(void* const* d_in, const int* in_sizes, int n_in,
                              void* d_out, int out_size, void* d_ws, size_t ws_size,
                              hipStream_t stream) {
    const float* X  = (const float*)d_in[0];   // [8][64][1024]
    const float* W0 = (const float*)d_in[1];   // [8][1024][1024]
    float* out = (float*)d_out;                // [8][64][1024]
    float* G   = (float*)d_ws;                 // [8][1088][64] fp32 = 2.23 MB

    gemm_kernel<<<BB * NTILES, 1024, 0, stream>>>(X, W0, G);
    scan_kernel<<<1024, 512, 0, stream>>>(G, out);
}

// Round 6
// 44.999 us; speedup vs baseline: 1.4426x; 1.4426x over previous
//
#include <hip/hip_runtime.h>
#include <hip/hip_bf16.h>

// Oja scan, reformulated. G[b][n][t] = row_n . x_t for n in [0,1088):
// rows 0..1023 = W0 rows, rows 1024..1087 = X rows (=> S = X X^T).
// Scan uses the exact projected Oja recurrence:
//   u[j] = W_t . x_j :  y_t = sigmoid(u[t]);  u <- (1-lr*y^2)*u + (lr*y)*S[t,:]
// R6 gemm: W channel-hotspotting fix — stage contiguous 16-row x 512-k
// panels into LDS via global_load_lds (1-KB contiguous chunks), padded
// stride 516 floats for bank spread. 4 blocks/CU overlap stage/compute.

#define BB 8
#define TT 64
#define NI 1024
#define NO 1024
#define NTOT 1088            // 1024 W rows + 64 X rows
#define NTILES 68            // NTOT/16
#define PAD 516              // LDS row stride in floats (512 + 4)

typedef __attribute__((ext_vector_type(8))) short bf16x8;
typedef __attribute__((ext_vector_type(4))) float f32x4;

__device__ __forceinline__ short f2bf(float f) {
    __hip_bfloat16 h = __float2bfloat16(f);
    return __builtin_bit_cast(short, h);
}

__device__ __forceinline__ bf16x8 cvt8(float4 lo, float4 hi) {
    bf16x8 r;
    r[0] = f2bf(lo.x); r[1] = f2bf(lo.y); r[2] = f2bf(lo.z); r[3] = f2bf(lo.w);
    r[4] = f2bf(hi.x); r[5] = f2bf(hi.y); r[6] = f2bf(hi.z); r[7] = f2bf(hi.w);
    return r;
}

// ---------- Kernel 1: G[b][n][t] via MFMA, LDS-staged A panel ----------
// Block: 256 thr = 4 waves; one 16-row n-tile; wave w owns t-tile w*16.
__global__ __launch_bounds__(256, 4)
void gemm_kernel(const float* __restrict__ X, const float* __restrict__ W0,
                 float* __restrict__ G)
{
    __shared__ float As[16 * PAD];   // 33,024 B

    const int lane = threadIdx.x & 63;
    const int wave = threadIdx.x >> 6;
    const int b  = blockIdx.x & 7;       // blockIdx%8 = batch -> XCD-local X
    const int nt = blockIdx.x >> 3;
    const int n0 = nt * 16;
    const int t0 = wave * 16;

    const int r  = lane & 15;            // row within tile
    const int kb = lane >> 4;            // k-block 0..3 (8 k's each)

    const float* __restrict__ Xb = X + (size_t)b * TT * NI;
    const float* __restrict__ Abase =
        (n0 < NO) ? (W0 + ((size_t)b * NO + n0) * NI)
                  : (Xb + (size_t)(n0 - NO) * NI);
    const float* __restrict__ Brow = Xb + (size_t)(t0 + r) * NI + kb * 8;

    f32x4 acc = {0.f, 0.f, 0.f, 0.f};

    for (int h = 0; h < 2; ++h) {
        // stage 16 rows x 512 k: wave w -> rows w*4..w*4+3, 2x 1-KB chunks each.
        // Each issue: 1 KB CONTIGUOUS global -> linear LDS (lane x 16 B).
#pragma unroll
        for (int i = 0; i < 4; ++i) {
            const int rw = wave * 4 + i;
#pragma unroll
            for (int c = 0; c < 2; ++c) {
                const float* src = Abase + (size_t)rw * NI + h * 512 + c * 256 + lane * 4;
                float* dst = &As[rw * PAD + c * 256];
                __builtin_amdgcn_global_load_lds(
                    (const __attribute__((address_space(1))) void*)src,
                    (__attribute__((address_space(3))) void*)dst,
                    16, 0, 0);
            }
        }
        __syncthreads();   // drains vmcnt (compiler) + all waves see panel

#pragma unroll 4
        for (int kk = 0; kk < 16; ++kk) {
            const float* ap = &As[r * PAD + kk * 32 + kb * 8];
            const float4 a0 = *reinterpret_cast<const float4*>(ap);
            const float4 a1 = *reinterpret_cast<const float4*>(ap + 4);
            const float* bp = Brow + h * 512 + kk * 32;
            const float4 b0 = *reinterpret_cast<const float4*>(bp);
            const float4 b1 = *reinterpret_cast<const float4*>(bp + 4);
            acc = __builtin_amdgcn_mfma_f32_16x16x32_bf16(cvt8(a0, a1), cvt8(b0, b1),
                                                          acc, 0, 0, 0);
        }
        __syncthreads();   // protect As before restaging
    }

    // D layout: col t = lane&15, row n = (lane>>4)*4 + rr   [m89-verified]
    const int tcol = lane & 15;
    const int mrow = (lane >> 4) * 4;
#pragma unroll
    for (int rr = 0; rr < 4; ++rr)
        G[((size_t)b * NTOT + n0 + mrow + rr) * TT + t0 + tcol] = acc[rr];
}

// ---------- Kernel 2: exact projected-Oja scan per (b,o) row ----------
__global__ __launch_bounds__(512, 8)
void scan_kernel(const float* __restrict__ G, float* __restrict__ out)
{
    __shared__ float Sl[TT][TT];      // 16 KB: S[b]
    __shared__ float ybuf[8][TT + 1]; // per-wave y trajectory (padded)

    const int tid  = threadIdx.x;
    const int lane = tid & 63;
    const int wave = tid >> 6;
    const int row  = blockIdx.x * 8 + wave;   // 0..8191
    const int b = row >> 10;                  // 128 blocks per batch
    const int o = row & 1023;

    // stage S[b] = G rows 1024..1087 (4096 contiguous floats)
    {
        const float4* __restrict__ src =
            reinterpret_cast<const float4*>(G + ((size_t)b * NTOT + NO) * TT);
        float4* dst = reinterpret_cast<float4*>(&Sl[0][0]);
        dst[tid]       = src[tid];
        dst[tid + 512] = src[tid + 512];
    }

    // u[lane] = W_0 . x_lane for this row (contiguous 64 floats)
    float u = G[((size_t)b * NTOT + o) * TT + lane];

    __syncthreads();

    const float lr = 1.0f / 1024.0f;
    float yslot = 0.0f;
    float srow = Sl[0][lane];
#pragma unroll
    for (int t = 0; t < TT; ++t) {
        const float srow_next = (t + 1 < TT) ? Sl[t + 1][lane] : 0.0f;
        const float sg = __int_as_float(__builtin_amdgcn_readlane(__float_as_int(u), t));
        const float e  = __expf(-sg);
        const float y  = __builtin_amdgcn_rcpf(1.0f + e);
        yslot = (lane == t) ? y : yslot;
        const float c2 = lr * y;                 // lr*y
        const float c1 = fmaf(-c2, y, 1.0f);     // 1 - lr*y^2
        u = fmaf(c1, u, c2 * srow);              // u <- c1*u + c2*S[t,:]
        srow = srow_next;
    }

    // coalesce output: bounce through LDS, then 32B-contiguous stores
    ybuf[wave][lane] = yslot;                    // lane = t
    __syncthreads();
    const int t  = tid >> 3;                     // 0..63
    const int oo = tid & 7;                      // 0..7
    const int o0 = (blockIdx.x & 127) * 8;
    out[(size_t)b * TT * NO + (size_t)t * NO + o0 + oo] = ybuf[oo][t];
}

extern "C" void kernel_launch(void* const* d_in, const int* in_sizes, int n_in,
                              void* d_out, int out_size, void* d_ws, size_t ws_size,
                              hipStream_t stream) {
    const float* X  = (const float*)d_in[0];   // [8][64][1024]
    const float* W0 = (const float*)d_in[1];   // [8][1024][1024]
    float* out = (float*)d_out;                // [8][64][1024]
    float* G   = (float*)d_ws;                 // [8][1088][64] fp32 = 2.23 MB

    gemm_kernel<<<BB * NTILES, 256, 0, stream>>>(X, W0, G);
    scan_kernel<<<1024, 512, 0, stream>>>(G, out);
}

// Round 7
// 40.260 us; speedup vs baseline: 1.6124x; 1.1177x over previous
//
#include <hip/hip_runtime.h>
#include <hip/hip_bf16.h>

// Oja scan, reformulated. G[b][n][t] = row_n . x_t for n in [0,1088):
// rows 0..1023 = W0 rows, rows 1024..1087 = X rows (=> S = X X^T).
// Scan: exact projected Oja recurrence on u[j] = W_t . x_j:
//   y_t = sigmoid(u[t]);  u <- (1-lr*y^2)*u + (lr*y)*S[t,:]
// R7: zero cvt in the MFMA inner loop.
//   k0: X -> bf16 once (1 MB).
//   k1: A-panel reg-staged to LDS as bf16 (cvt once per block, not per wave),
//       stride 1032 bf16 -> balanced conflict-free ds_read_b128;
//       inner loop = ds_read_b128 + 16B global B + MFMA only.

#define BB 8
#define TT 64
#define NI 1024
#define NO 1024
#define NTOT 1088            // 1024 W rows + 64 X rows
#define NTILES 68            // NTOT/16
#define PADBF 1032           // LDS row stride in bf16 (1024 + 8)

typedef __attribute__((ext_vector_type(8))) short bf16x8;
typedef __attribute__((ext_vector_type(4))) float f32x4;

__device__ __forceinline__ short f2bf(float f) {
    __hip_bfloat16 h = __float2bfloat16(f);
    return __builtin_bit_cast(short, h);
}

// ---------- Kernel 0: X (f32) -> Xb16 (bf16), 524288 elements ----------
__global__ __launch_bounds__(256)
void xcvt_kernel(const float* __restrict__ X, ushort* __restrict__ Xb16)
{
    const int i = blockIdx.x * 256 + threadIdx.x;   // float4 index, 131072 total
    const float4 v = *reinterpret_cast<const float4*>(X + (size_t)i * 4);
    short4 s;
    s.x = f2bf(v.x); s.y = f2bf(v.y); s.z = f2bf(v.z); s.w = f2bf(v.w);
    *reinterpret_cast<short4*>(Xb16 + (size_t)i * 4) = s;
}

// ---------- Kernel 1: G[b][n][t] via MFMA, bf16 LDS A panel ----------
// Block: 256 thr = 4 waves; one 16-row n-tile; wave w owns t-tile w*16.
__global__ __launch_bounds__(256, 4)
void gemm_kernel(const float* __restrict__ X, const float* __restrict__ W0,
                 const ushort* __restrict__ Xb16, float* __restrict__ G)
{
    __shared__ ushort As[16 * PADBF];   // 33,024 B

    const int tid  = threadIdx.x;
    const int lane = tid & 63;
    const int wave = tid >> 6;
    const int b  = blockIdx.x & 7;       // blockIdx%8 = batch -> XCD-local X
    const int nt = blockIdx.x >> 3;
    const int n0 = nt * 16;
    const int t0 = wave * 16;

    const int r  = lane & 15;            // row within tile
    const int kb = lane >> 4;            // k-block 0..3 (8 k's each)

    const float* __restrict__ Abase =
        (n0 < NO) ? (W0 + ((size_t)b * NO + n0) * NI)
                  : (X + ((size_t)b * TT + (n0 - NO)) * NI);

    // ---- stage: 16 rows x 1024 f32 -> bf16 LDS, cvt once per block ----
    // iter j: 256 threads load row j's 4 KB contiguously (thread -> float4),
    // convert, ds_write_b64 at stride-1032 position.
#pragma unroll 8
    for (int j = 0; j < 16; ++j) {
        const float4 v = *reinterpret_cast<const float4*>(Abase + (size_t)j * NI + tid * 4);
        short4 s;
        s.x = f2bf(v.x); s.y = f2bf(v.y); s.z = f2bf(v.z); s.w = f2bf(v.w);
        *reinterpret_cast<short4*>(&As[j * PADBF + tid * 4]) = s;
    }
    __syncthreads();

    // ---- MFMA loop: pure ds_read_b128 + 16B global B + MFMA ----
    const ushort* __restrict__ Bbase =
        Xb16 + ((size_t)b * TT + t0 + r) * NI + kb * 8;
    const ushort* __restrict__ Ap = &As[r * PADBF + kb * 8];

    f32x4 acc = {0.f, 0.f, 0.f, 0.f};
#pragma unroll 8
    for (int kk = 0; kk < 32; ++kk) {
        const bf16x8 a  = *reinterpret_cast<const bf16x8*>(Ap + kk * 32);
        const bf16x8 bv = *reinterpret_cast<const bf16x8*>(Bbase + kk * 32);
        acc = __builtin_amdgcn_mfma_f32_16x16x32_bf16(a, bv, acc, 0, 0, 0);
    }

    // D layout: col t = lane&15, row n = (lane>>4)*4 + rr   [m89-verified]
    const int tcol = lane & 15;
    const int mrow = (lane >> 4) * 4;
#pragma unroll
    for (int rr = 0; rr < 4; ++rr)
        G[((size_t)b * NTOT + n0 + mrow + rr) * TT + t0 + tcol] = acc[rr];
}

// ---------- Kernel 2: exact projected-Oja scan per (b,o) row ----------
__global__ __launch_bounds__(512, 8)
void scan_kernel(const float* __restrict__ G, float* __restrict__ out)
{
    __shared__ float Sl[TT][TT];      // 16 KB: S[b]
    __shared__ float ybuf[8][TT + 1]; // per-wave y trajectory (padded)

    const int tid  = threadIdx.x;
    const int lane = tid & 63;
    const int wave = tid >> 6;
    const int row  = blockIdx.x * 8 + wave;   // 0..8191
    const int b = row >> 10;                  // 128 blocks per batch
    const int o = row & 1023;

    // stage S[b] = G rows 1024..1087 (4096 contiguous floats)
    {
        const float4* __restrict__ src =
            reinterpret_cast<const float4*>(G + ((size_t)b * NTOT + NO) * TT);
        float4* dst = reinterpret_cast<float4*>(&Sl[0][0]);
        dst[tid]       = src[tid];
        dst[tid + 512] = src[tid + 512];
    }

    // u[lane] = W_0 . x_lane for this row (contiguous 64 floats)
    float u = G[((size_t)b * NTOT + o) * TT + lane];

    __syncthreads();

    const float lr = 1.0f / 1024.0f;
    float yslot = 0.0f;
    float srow = Sl[0][lane];
#pragma unroll
    for (int t = 0; t < TT; ++t) {
        const float srow_next = (t + 1 < TT) ? Sl[t + 1][lane] : 0.0f;
        const float sg = __int_as_float(__builtin_amdgcn_readlane(__float_as_int(u), t));
        const float e  = __expf(-sg);
        const float y  = __builtin_amdgcn_rcpf(1.0f + e);
        yslot = (lane == t) ? y : yslot;
        const float c2 = lr * y;                 // lr*y
        const float c1 = fmaf(-c2, y, 1.0f);     // 1 - lr*y^2
        u = fmaf(c1, u, c2 * srow);              // u <- c1*u + c2*S[t,:]
        srow = srow_next;
    }

    // coalesce output: bounce through LDS, then 32B-contiguous stores
    ybuf[wave][lane] = yslot;                    // lane = t
    __syncthreads();
    const int t  = tid >> 3;                     // 0..63
    const int oo = tid & 7;                      // 0..7
    const int o0 = (blockIdx.x & 127) * 8;
    out[(size_t)b * TT * NO + (size_t)t * NO + o0 + oo] = ybuf[oo][t];
}

extern "C" void kernel_launch(void* const* d_in, const int* in_sizes, int n_in,
                              void* d_out, int out_size, void* d_ws, size_t ws_size,
                              hipStream_t stream) {
    const float* X  = (const float*)d_in[0];   // [8][64][1024]
    const float* W0 = (const float*)d_in[1];   // [8][1024][1024]
    float* out = (float*)d_out;                // [8][64][1024]

    float*  G    = (float*)d_ws;                          // [8][1088][64] = 2,228,224 B
    ushort* Xb16 = (ushort*)((char*)d_ws + 2228224);      // [8][64][1024] bf16 = 1 MB

    xcvt_kernel<<<512, 256, 0, stream>>>(X, Xb16);
    gemm_kernel<<<BB * NTILES, 256, 0, stream>>>(X, W0, Xb16, G);
    scan_kernel<<<1024, 512, 0, stream>>>(G, out);
}